// Round 8
// baseline (650.861 us; speedup 1.0000x reference)
//
#include <hip/hip_runtime.h>
#include <hip/hip_bf16.h>

#define Bz 512
#define NF 512
#define TT 64
#define HIDZ 1024
#define LATZ 2

// output layout (floats)
static const size_t OFF_XAE   = 0;                                  // 512*512*64
static const size_t OFF_Y     = (size_t)Bz * NF * TT;               // 16777216
static const size_t OFF_DMD   = OFF_Y + (size_t)Bz * LATZ * TT;     // 16842752
static const size_t OFF_AE    = OFF_DMD + 1;                        // 16842753
static const size_t OFF_YPRED = OFF_AE + 1;                         // 16842754
static const size_t OFF_AMAT  = OFF_YPRED + (size_t)Bz * LATZ * TT; // 16908290
static const size_t OFF_PRED  = OFF_AMAT + (size_t)1024 * 1024;     // 17956866

// workspace layout (float offsets)
#define WS_G     0         // 63*63
#define WS_GINV  4096
#define WS_PROJ  8192
#define WS_P     16384     // 63*1024 -> ends 80896
#define WS_W     1441792   // 63*63
#define WS_GP    1445888   // 16*3969 partial G
#define WS_WP    1511424   // 16*3969 partial W
#define WS_PP    1576960   // 16*3969 partial P@Y-
#define WS_U     1642496   // 64*64 chain vectors (stride 64)
#define WS_WD2T  3538944   // 1 MB ushort: Wd2 bf16 A-frag layout
#define WS_WE1H  3801088   // 1 MB ushort: We1 hi A-frags
#define WS_WE1L  4063232   // 1 MB ushort: We1 lo A-frags

typedef __attribute__((ext_vector_type(8))) short bf16x8;
typedef __attribute__((ext_vector_type(4))) float f32x4;

__device__ __forceinline__ unsigned short f2bf(float f) {
  unsigned u = __float_as_uint(f);
  unsigned r = (u + 0x7fffu + ((u >> 16) & 1u)) >> 16;
  return (unsigned short)r;
}
__device__ __forceinline__ float bf2f(unsigned short h) {
  return __uint_as_float((unsigned)h << 16);
}
__device__ __forceinline__ uint4 pack8(const unsigned short* v) {
  return make_uint4((unsigned)v[0] | ((unsigned)v[1] << 16),
                    (unsigned)v[2] | ((unsigned)v[3] << 16),
                    (unsigned)v[4] | ((unsigned)v[5] << 16),
                    (unsigned)v[6] | ((unsigned)v[7] << 16));
}

__device__ inline float blockReduceSum(float v) {
  __shared__ float sh[16];
  int lane = threadIdx.x & 63;
  int wid  = threadIdx.x >> 6;
#pragma unroll
  for (int off = 32; off > 0; off >>= 1) v += __shfl_down(v, off, 64);
  if (lane == 0) sh[wid] = v;
  __syncthreads();
  int nw = blockDim.x >> 6;
  v = (threadIdx.x < (unsigned)nw) ? sh[threadIdx.x] : 0.f;
  if (wid == 0) {
#pragma unroll
    for (int off = 8; off > 0; off >>= 1) v += __shfl_down(v, off, 64);
  }
  return v;
}

// prep: We1 -> hi/lo A-frags (bid<256), Wd2 -> bf16 A-frags (bid<512), zero losses (bid==512)
__global__ void k_prep(const float* __restrict__ We1,
                       unsigned short* __restrict__ ah, unsigned short* __restrict__ al,
                       const float* __restrict__ Wd2, unsigned short* __restrict__ at,
                       float* dmd, float* ae, float* pred) {
  int bid = blockIdx.x, tid = threadIdx.x;
  if (bid < 256) {
    int s = bid * 256 + tid;              // 65536 slots
    int l = s & 63, mfg = (s >> 6) & 63, kt = s >> 12;
    int m = mfg * 16 + (l & 15);
    int k0 = kt * 32 + (l >> 4) * 8;
    unsigned short h[8], lo[8];
#pragma unroll
    for (int e = 0; e < 8; ++e) {
      float v = We1[(size_t)(k0 + e) * HIDZ + m];
      h[e] = f2bf(v);
      lo[e] = f2bf(v - bf2f(h[e]));
    }
    *(uint4*)(ah + (size_t)s * 8) = pack8(h);
    *(uint4*)(al + (size_t)s * 8) = pack8(lo);
  } else if (bid < 512) {
    int s = (bid - 256) * 256 + tid;      // 65536 slots
    int l = s & 63;
    int frag = s >> 6;
    int mf = frag & 31, kt = frag >> 5;
    int n = mf * 16 + (l & 15);
    int kbase = kt * 32 + (l >> 4) * 8;
    unsigned short v[8];
#pragma unroll
    for (int e = 0; e < 8; ++e) v[e] = f2bf(Wd2[(size_t)(kbase + e) * NF + n]);
    *(uint4*)(at + (size_t)s * 8) = pack8(v);
  } else if (tid == 0) {
    *dmd = 0.f; *ae = 0.f; *pred = 0.f;
  }
}

// stage 4 x elements -> hi and lo uint2 in frag order
__device__ __forceinline__ void stage_x(const float* __restrict__ xb, int kt,
                                        int nf_s, int ls, int half8,
                                        uint2* dh, uint2* dl) {
  int k0 = kt * 32 + (ls >> 4) * 8 + half8 * 4;
  int t_s = nf_s * 16 + (ls & 15);
  const float* xp = xb + (size_t)k0 * TT + t_s;
  float v[4];
#pragma unroll
  for (int e = 0; e < 4; ++e) v[e] = xp[e * TT];
  unsigned short h[4], lo[4];
#pragma unroll
  for (int e = 0; e < 4; ++e) {
    h[e] = f2bf(v[e]);
    lo[e] = f2bf(v[e] - bf2f(h[e]));
  }
  *dh = make_uint2((unsigned)h[0] | ((unsigned)h[1] << 16),
                   (unsigned)h[2] | ((unsigned)h[3] << 16));
  *dl = make_uint2((unsigned)lo[0] | ((unsigned)lo[1] << 16),
                   (unsigned)lo[2] | ((unsigned)lo[3] << 16));
}

// GEMM1: one block per b, 8 waves, all 1024 h. Split-bf16 3-pass MFMA,
// double-buffered x staging (each thread stages 4 elems -> x read 1x).
// Epilogue: tanh + We2 reduce, deterministic, writes y directly (+be2).
__global__ __launch_bounds__(512, 2) void k_gemm1m(const float* __restrict__ x,
    const unsigned short* __restrict__ we1h, const unsigned short* __restrict__ we1l,
    const float* __restrict__ be1, const float* __restrict__ We2,
    const float* __restrict__ be2, float* __restrict__ y) {
  __shared__ __align__(16) uint4 bh4[2][4][64], bl4[2][4][64];
  __shared__ float yredl[8][2][64];
  int b = blockIdx.x;
  int tid = threadIdx.x, w = tid >> 6, l = tid & 63, q = l >> 4, c = l & 15;
  const float* xb = x + (size_t)b * NF * TT;
  // staging role: 512 threads cover 2048 elems/kt (4 each)
  int half8 = tid >> 8;                    // elems 0-3 vs 4-7
  int rest = tid & 255;
  int nf_s = rest >> 6, ls = rest & 63;
  f32x4 acc[8][4];
#pragma unroll
  for (int i = 0; i < 8; ++i)
#pragma unroll
    for (int j = 0; j < 4; ++j) acc[i][j] = (f32x4)(0.f);
  stage_x(xb, 0, nf_s, ls, half8, (uint2*)&bh4[0][nf_s][ls] + half8,
          (uint2*)&bl4[0][nf_s][ls] + half8);
  __syncthreads();
  for (int kt = 0; kt < 16; ++kt) {
    int cur = kt & 1;
    if (kt + 1 < 16)
      stage_x(xb, kt + 1, nf_s, ls, half8, (uint2*)&bh4[cur ^ 1][nf_s][ls] + half8,
              (uint2*)&bl4[cur ^ 1][nf_s][ls] + half8);
    bf16x8 bhf[4], blf[4];
#pragma unroll
    for (int nf = 0; nf < 4; ++nf) {
      bhf[nf] = *(bf16x8*)&bh4[cur][nf][l];
      blf[nf] = *(bf16x8*)&bl4[cur][nf][l];
    }
#pragma unroll
    for (int mf = 0; mf < 8; ++mf) {
      size_t slot = ((size_t)kt * 64 + w * 8 + mf) * 64 + l;
      bf16x8 ah = *(const bf16x8*)(we1h + slot * 8);
      bf16x8 al = *(const bf16x8*)(we1l + slot * 8);
#pragma unroll
      for (int nf = 0; nf < 4; ++nf) {
        acc[mf][nf] = __builtin_amdgcn_mfma_f32_16x16x32_bf16(ah, bhf[nf], acc[mf][nf], 0, 0, 0);
        acc[mf][nf] = __builtin_amdgcn_mfma_f32_16x16x32_bf16(ah, blf[nf], acc[mf][nf], 0, 0, 0);
        acc[mf][nf] = __builtin_amdgcn_mfma_f32_16x16x32_bf16(al, bhf[nf], acc[mf][nf], 0, 0, 0);
      }
    }
    __syncthreads();
  }
  // epilogue: tanh + We2 reduce
  float p0[4] = {0.f, 0.f, 0.f, 0.f}, p1[4] = {0.f, 0.f, 0.f, 0.f};
#pragma unroll
  for (int mf = 0; mf < 8; ++mf) {
    int hbase = w * 128 + mf * 16 + q * 4;
#pragma unroll
    for (int r = 0; r < 4; ++r) {
      int hh = hbase + r;
      float bias = be1[hh];
      float w20 = We2[2 * hh], w21 = We2[2 * hh + 1];
#pragma unroll
      for (int nf = 0; nf < 4; ++nf) {
        float hv = tanhf(acc[mf][nf][r] + bias);
        p0[nf] += hv * w20;
        p1[nf] += hv * w21;
      }
    }
  }
#pragma unroll
  for (int nf = 0; nf < 4; ++nf) {
    p0[nf] += __shfl_xor(p0[nf], 16, 64); p0[nf] += __shfl_xor(p0[nf], 32, 64);
    p1[nf] += __shfl_xor(p1[nf], 16, 64); p1[nf] += __shfl_xor(p1[nf], 32, 64);
  }
  if (q == 0) {
#pragma unroll
    for (int nf = 0; nf < 4; ++nf) {
      yredl[w][0][nf * 16 + c] = p0[nf];
      yredl[w][1][nf * 16 + c] = p1[nf];
    }
  }
  __syncthreads();
  if (tid < 128) {
    int lat = tid >> 6, t = tid & 63;
    float s = be2[lat];
#pragma unroll
    for (int ww = 0; ww < 8; ++ww) s += yredl[ww][lat][t];
    y[((size_t)b * LATZ + lat) * TT + t] = s;
  }
}

__device__ __forceinline__ void stage_hd(int kt, unsigned short* dst, int q,
                                         float y0t, float y1t,
                                         const float* __restrict__ Wd1,
                                         const float* __restrict__ bd1) {
  int k = kt * 32 + q * 8;
  float4 w0a = *(const float4*)&Wd1[k];
  float4 w0b = *(const float4*)&Wd1[k + 4];
  float4 w1a = *(const float4*)&Wd1[HIDZ + k];
  float4 w1b = *(const float4*)&Wd1[HIDZ + k + 4];
  float4 ba  = *(const float4*)&bd1[k];
  float4 bb  = *(const float4*)&bd1[k + 4];
  float h[8];
  h[0] = tanhf(y0t * w0a.x + y1t * w1a.x + ba.x);
  h[1] = tanhf(y0t * w0a.y + y1t * w1a.y + ba.y);
  h[2] = tanhf(y0t * w0a.z + y1t * w1a.z + ba.z);
  h[3] = tanhf(y0t * w0a.w + y1t * w1a.w + ba.w);
  h[4] = tanhf(y0t * w0b.x + y1t * w1b.x + bb.x);
  h[5] = tanhf(y0t * w0b.y + y1t * w1b.y + bb.y);
  h[6] = tanhf(y0t * w0b.z + y1t * w1b.z + bb.z);
  h[7] = tanhf(y0t * w0b.w + y1t * w1b.w + bb.w);
  unsigned short hv[8];
#pragma unroll
  for (int e = 0; e < 8; ++e) hv[e] = f2bf(h[e]);
  *(uint4*)dst = pack8(hv);
}

// GEMM4 via MFMA + fused ae_loss (t=0 column: c==0, t2==0)
__global__ __launch_bounds__(256, 2) void k_gemm4m(const float* __restrict__ y,
                                                   const float* __restrict__ Wd1,
                                                   const float* __restrict__ bd1,
                                                   const unsigned short* __restrict__ at,
                                                   const float* __restrict__ bd2,
                                                   const float* __restrict__ x,
                                                   float* __restrict__ xae,
                                                   float* __restrict__ ae_out) {
  __shared__ __align__(16) unsigned short bbuf[2][4][64][8];
  __shared__ float ys[2][64];
  int b = blockIdx.x, tid = threadIdx.x;
  int w = tid >> 6, l = tid & 63;
  int c = l & 15, q = l >> 4;
  if (tid < 128) ys[tid >> 6][tid & 63] = y[((size_t)b * LATZ + (tid >> 6)) * TT + (tid & 63)];
  __syncthreads();
  int t_s = w * 16 + c;
  float y0t = ys[0][t_s], y1t = ys[1][t_s];
  f32x4 acc[8][4];
#pragma unroll
  for (int i = 0; i < 8; ++i)
#pragma unroll
    for (int j = 0; j < 4; ++j) acc[i][j] = (f32x4)(0.f);
  const bf16x8* A = (const bf16x8*)at;
  stage_hd(0, &bbuf[0][w][l][0], q, y0t, y1t, Wd1, bd1);
  for (int kt = 0; kt < 32; ++kt) {
    __syncthreads();
    if (kt + 1 < 32) stage_hd(kt + 1, &bbuf[(kt + 1) & 1][w][l][0], q, y0t, y1t, Wd1, bd1);
    bf16x8 bf[4];
#pragma unroll
    for (int t2 = 0; t2 < 4; ++t2) bf[t2] = *(const bf16x8*)&bbuf[kt & 1][t2][l][0];
    bf16x8 af[8];
#pragma unroll
    for (int mf = 0; mf < 8; ++mf) af[mf] = A[(size_t)((kt * 32 + w * 8 + mf) * 64) + l];
#pragma unroll
    for (int mf = 0; mf < 8; ++mf)
#pragma unroll
      for (int t2 = 0; t2 < 4; ++t2)
        acc[mf][t2] = __builtin_amdgcn_mfma_f32_16x16x32_bf16(af[mf], bf[t2], acc[mf][t2], 0, 0, 0);
  }
#pragma unroll
  for (int mf = 0; mf < 8; ++mf) {
    int nb = w * 128 + mf * 16 + q * 4;
#pragma unroll
    for (int r = 0; r < 4; ++r) {
      int n = nb + r;
      float bias = bd2[n];
#pragma unroll
      for (int t2 = 0; t2 < 4; ++t2)
        xae[((size_t)b * NF + n) * TT + t2 * 16 + c] = acc[mf][t2][r] + bias;
    }
  }
  // fused ae_loss: t=0 column held by lanes with c==0 in frag t2=0
  float aeacc = 0.f;
  if (c == 0) {
#pragma unroll
    for (int mf = 0; mf < 8; ++mf) {
#pragma unroll
      for (int r = 0; r < 4; ++r) {
        int n = w * 128 + mf * 16 + q * 4 + r;
        float d = x[((size_t)b * NF + n) * TT] - (acc[mf][0][r] + bd2[n]);
        aeacc += d * d;
      }
    }
  }
  float tot = blockReduceSum(aeacc);
  if (tid == 0) atomicAdd(ae_out, tot * (1.f / 262144.f));
}

// Chunked G = Y-^T Y- and W = Y-^T Y+ partials
__global__ __launch_bounds__(256) void k_Gall(const float* __restrict__ y,
                                              float* __restrict__ Gp, float* __restrict__ Wp) {
  __shared__ float ys[64][65];
  int cb = blockIdx.x, tid = threadIdx.x;
#pragma unroll
  for (int p = 0; p < 16; ++p) {
    int f = tid + p * 256;
    int rr = f >> 6, cc = f & 63;
    ys[rr][cc] = y[(size_t)(cb * 64 + rr) * 64 + cc];
  }
  __syncthreads();
#pragma unroll
  for (int p = 0; p < 16; ++p) {
    int o = tid + p * 256;
    if (o < 3969) {
      int i = o / 63, j = o % 63;
      float gs = 0.f, wsv = 0.f;
#pragma unroll
      for (int rr = 0; rr < 64; ++rr) {
        float yi = ys[rr][i];
        gs  += yi * ys[rr][j];
        wsv += yi * ys[rr][j + 1];
      }
      Gp[cb * 3969 + o] = gs;
      Wp[cb * 3969 + o] = wsv;
    }
  }
}

// G, W = fixed-order sum of 16 partials
__global__ void k_Gred(const float* __restrict__ Gp, const float* __restrict__ Wp,
                       float* __restrict__ G, float* __restrict__ W) {
  int idx = blockIdx.x * 256 + threadIdx.x;
  if (idx >= 2 * 3969) return;
  int sel = idx >= 3969;
  int o = idx - sel * 3969;
  const float* src = sel ? Wp : Gp;
  float s = 0.f;
#pragma unroll
  for (int cb = 0; cb < 16; ++cb) s += src[cb * 3969 + o];
  (sel ? W : G)[o] = s;
}

// GJ inverse (register-resident) + 63-dim power chain, single wave.
// M = Ginv*W rows in regs; u_{t+1} = M u_t; u_0 = Ginv*G[:,0]; U[t*64+i] = u_t[i].
__global__ __launch_bounds__(64, 1) void k_invchain(const float* __restrict__ G,
                                                    const float* __restrict__ W,
                                                    float* __restrict__ Ginv,
                                                    float* __restrict__ U) {
  __shared__ float wl[63][64];
  __shared__ float zl[64];
  __shared__ float ul[64];
  int i = threadIdx.x;
  float a[126];
  if (i < 63) {
#pragma unroll
    for (int j = 0; j < 63; ++j) a[j] = G[i * 63 + j];
  } else {
#pragma unroll
    for (int j = 0; j < 63; ++j) a[j] = (j == 0) ? 1.f : 0.f;
  }
#pragma unroll
  for (int j = 0; j < 63; ++j) a[63 + j] = (i == j) ? 1.f : 0.f;
#pragma unroll
  for (int k = 0; k < 63; ++k) {
    float pivot = __shfl(a[k], k, 64);
    float rp = 1.f / pivot;
    float m = a[k];
    bool isk = (i == k);
#pragma unroll
    for (int j = k; j < 126; ++j) {
      float t = __shfl(a[j], k, 64) * rp;
      a[j] = isk ? t : (a[j] - m * t);
    }
  }
  if (i < 63) {
#pragma unroll
    for (int j = 0; j < 63; ++j) Ginv[i * 63 + j] = a[63 + j];
    for (int k = 0; k < 63; ++k) wl[k][i] = W[k * 63 + i];
    zl[i] = G[i * 63];
  }
  __syncthreads();
  float m[63];
#pragma unroll
  for (int j = 0; j < 63; ++j) {
    float s = 0.f;
#pragma unroll
    for (int k = 0; k < 63; ++k) s += a[63 + k] * wl[k][j];
    m[j] = s;
  }
  float u = 0.f;
#pragma unroll
  for (int k = 0; k < 63; ++k) u += a[63 + k] * zl[k];
  for (int t = 0; t < 64; ++t) {
    if (i < 63) U[t * 64 + i] = u;
    ul[i] = (i < 63) ? u : 0.f;
    __syncthreads();
    float un = 0.f;
#pragma unroll
    for (int j = 0; j < 63; ++j) un += m[j] * ul[j];
    __syncthreads();
    u = un;
  }
}

// P slice (Ginv * Y-^T for cols cb*64..) to global+LDS, then proj partial (P@Y-)
__global__ __launch_bounds__(256) void k_Pprojc(const float* __restrict__ y,
                                                const float* __restrict__ Ginv,
                                                float* __restrict__ P,
                                                float* __restrict__ Pp) {
  __shared__ float ys[64][65];
  __shared__ float ps[63][64];
  int cb = blockIdx.x, tid = threadIdx.x;
#pragma unroll
  for (int p = 0; p < 16; ++p) {
    int f = tid + p * 256;
    ys[f >> 6][f & 63] = y[(size_t)(cb * 64 + (f >> 6)) * 64 + (f & 63)];
  }
  __syncthreads();
#pragma unroll
  for (int p = 0; p < 16; ++p) {
    int o = tid + p * 256;
    if (o < 4032) {
      int i = o >> 6, rr = o & 63;
      if (i < 63) {
        float s = 0.f;
#pragma unroll
        for (int j = 0; j < 63; ++j) s += Ginv[i * 63 + j] * ys[rr][j];
        ps[i][rr] = s;
        P[(size_t)i * 1024 + cb * 64 + rr] = s;
      }
    }
  }
  __syncthreads();
#pragma unroll
  for (int p = 0; p < 16; ++p) {
    int o = tid + p * 256;
    if (o < 3969) {
      int i = o / 63, j = o % 63;
      float s = 0.f;
#pragma unroll
      for (int rr = 0; rr < 64; ++rr) s += ps[i][rr] * ys[rr][j];
      Pp[cb * 3969 + o] = s;
    }
  }
}

// proj = I - fixed-order sum of partials
__global__ void k_projred(const float* __restrict__ Pp, float* __restrict__ proj) {
  int o = blockIdx.x * 256 + threadIdx.x;
  if (o >= 3969) return;
  int i = o / 63, j = o % 63;
  float s = 0.f;
#pragma unroll
  for (int cb = 0; cb < 16; ++cb) s += Pp[cb * 3969 + o];
  proj[o] = ((i == j) ? 1.f : 0.f) - s;
}

// Amat = Y+ @ P
__global__ __launch_bounds__(256) void k_Amat(const float* __restrict__ y,
                                              const float* __restrict__ P,
                                              float* __restrict__ amat_out) {
  __shared__ float Yp[64][65];
  __shared__ float Ps[63][64];
  int r0 = blockIdx.x * 64, p0 = blockIdx.y * 64;
  int tid = threadIdx.x, tx = tid & 15, ty = tid >> 4;
#pragma unroll
  for (int p = 0; p < 16; ++p) {
    int f = tid + p * 256;
    Yp[f >> 6][f & 63] = y[(size_t)(p0 + (f >> 6)) * 64 + (f & 63)];
  }
#pragma unroll
  for (int p = 0; p < 16; ++p) {
    int f = tid + p * 256;
    if (f < 4032) {
      int j = f >> 6, rr = f & 63;
      Ps[j][rr] = P[(size_t)j * 1024 + r0 + rr];
    }
  }
  __syncthreads();
  float acc[4][4] = {};
  for (int j = 0; j < 63; ++j) {
    float a0 = Yp[ty * 4 + 0][j + 1];
    float a1 = Yp[ty * 4 + 1][j + 1];
    float a2 = Yp[ty * 4 + 2][j + 1];
    float a3 = Yp[ty * 4 + 3][j + 1];
    float4 bv = *(float4*)&Ps[j][tx * 4];
    acc[0][0] += a0 * bv.x; acc[0][1] += a0 * bv.y; acc[0][2] += a0 * bv.z; acc[0][3] += a0 * bv.w;
    acc[1][0] += a1 * bv.x; acc[1][1] += a1 * bv.y; acc[1][2] += a1 * bv.z; acc[1][3] += a1 * bv.w;
    acc[2][0] += a2 * bv.x; acc[2][1] += a2 * bv.y; acc[2][2] += a2 * bv.z; acc[2][3] += a2 * bv.w;
    acc[3][0] += a3 * bv.x; acc[3][1] += a3 * bv.y; acc[3][2] += a3 * bv.z; acc[3][3] += a3 * bv.w;
  }
#pragma unroll
  for (int i = 0; i < 4; ++i) {
#pragma unroll
    for (int jj = 0; jj < 4; ++jj) {
      size_t idx = (size_t)(p0 + ty * 4 + i) * 1024 + r0 + tx * 4 + jj;
      amat_out[idx] = acc[i][jj];
    }
  }
}

// dmd_loss = sum((Y+ @ proj)^2)
__global__ __launch_bounds__(256) void k_dmdloss(const float* __restrict__ y,
                                                 const float* __restrict__ proj,
                                                 float* __restrict__ out_dmd) {
  __shared__ float ps[3969];
  int tid = threadIdx.x;
  for (int f = tid; f < 3969; f += 256) ps[f] = proj[f];
  __syncthreads();
  int p = blockIdx.x * 256 + tid;
  float yp[63];
#pragma unroll
  for (int k = 0; k < 63; ++k) yp[k] = y[(size_t)p * 64 + k + 1];
  float accv = 0.f;
  for (int j = 0; j < 63; ++j) {
    float s = 0.f;
#pragma unroll
    for (int k = 0; k < 63; ++k) s += yp[k] * ps[k * 63 + j];
    accv += s * s;
  }
  float tot = blockReduceSum(accv);
  if (tid == 0) atomicAdd(out_dmd, tot);
}

// y_pred = Y+ @ U^T per 64-row block; fused pred_loss
__global__ __launch_bounds__(256) void k_ypredloss(const float* __restrict__ y,
                                                   const float* __restrict__ U,
                                                   float* __restrict__ ypred,
                                                   float* __restrict__ pred_out) {
  __shared__ float yp[64][65];
  __shared__ float ul[64][65];
  int rb = blockIdx.x, tid = threadIdx.x;
#pragma unroll
  for (int p = 0; p < 16; ++p) {
    int f = tid + p * 256;
    int a = f >> 6, b2 = f & 63;
    yp[a][b2] = y[(size_t)(rb * 64 + a) * 64 + b2];
    ul[a][b2] = U[a * 64 + b2];
  }
  __syncthreads();
  int rr = tid >> 2, tg = tid & 3;
  float acc[16] = {};
  for (int j = 0; j < 63; ++j) {
    float yv = yp[rr][j + 1];
#pragma unroll
    for (int tt = 0; tt < 16; ++tt) acc[tt] += yv * ul[tg * 16 + tt][j];
  }
  float* op = ypred + (size_t)(rb * 64 + rr) * 64 + tg * 16;
  float se = 0.f;
#pragma unroll
  for (int tt = 0; tt < 16; ++tt) {
    float d = acc[tt] - yp[rr][tg * 16 + tt];
    se += d * d;
  }
#pragma unroll
  for (int e = 0; e < 8; ++e)
    *(float2*)&op[e * 2] = make_float2(acc[2 * e], acc[2 * e + 1]);
  float tot = blockReduceSum(se);
  if (tid == 0) atomicAdd(pred_out, tot * (1.f / 65536.f));
}

extern "C" void kernel_launch(void* const* d_in, const int* in_sizes, int n_in,
                              void* d_out, int out_size, void* d_ws, size_t ws_size,
                              hipStream_t stream) {
  (void)in_sizes; (void)n_in; (void)out_size; (void)ws_size;
  const float* x   = (const float*)d_in[0];
  const float* We1 = (const float*)d_in[1];
  const float* be1 = (const float*)d_in[2];
  const float* We2 = (const float*)d_in[3];
  const float* be2 = (const float*)d_in[4];
  const float* Wd1 = (const float*)d_in[5];
  const float* bd1 = (const float*)d_in[6];
  const float* Wd2 = (const float*)d_in[7];
  const float* bd2 = (const float*)d_in[8];
  float* out = (float*)d_out;
  float* wsf = (float*)d_ws;

  float* y_out = out + OFF_Y;
  unsigned short* wd2t = (unsigned short*)(wsf + WS_WD2T);
  unsigned short* we1h = (unsigned short*)(wsf + WS_WE1H);
  unsigned short* we1l = (unsigned short*)(wsf + WS_WE1L);

  k_prep<<<513, 256, 0, stream>>>(We1, we1h, we1l, Wd2, wd2t,
                                  out + OFF_DMD, out + OFF_AE, out + OFF_PRED);
  k_gemm1m<<<512, 512, 0, stream>>>(x, we1h, we1l, be1, We2, be2, y_out);
  k_gemm4m<<<512, 256, 0, stream>>>(y_out, Wd1, bd1, wd2t, bd2, x,
                                    out + OFF_XAE, out + OFF_AE);
  k_Gall<<<16, 256, 0, stream>>>(y_out, wsf + WS_GP, wsf + WS_WP);
  k_Gred<<<32, 256, 0, stream>>>(wsf + WS_GP, wsf + WS_WP, wsf + WS_G, wsf + WS_W);
  k_invchain<<<1, 64, 0, stream>>>(wsf + WS_G, wsf + WS_W, wsf + WS_GINV, wsf + WS_U);
  k_Pprojc<<<16, 256, 0, stream>>>(y_out, wsf + WS_GINV, wsf + WS_P, wsf + WS_PP);
  k_projred<<<16, 256, 0, stream>>>(wsf + WS_PP, wsf + WS_PROJ);
  k_Amat<<<dim3(16, 16), 256, 0, stream>>>(y_out, wsf + WS_P, out + OFF_AMAT);
  k_dmdloss<<<4, 256, 0, stream>>>(y_out, wsf + WS_PROJ, out + OFF_DMD);
  k_ypredloss<<<16, 256, 0, stream>>>(y_out, wsf + WS_U, out + OFF_YPRED, out + OFF_PRED);
}